// Round 3
// baseline (134.614 us; speedup 1.0000x reference)
//
#include <hip/hip_runtime.h>

#define NT 32
#define START_TAG 30
#define STOP_TAG 31
#define L2E 1.4426950408889634f
#define LN2 0.6931471805599453f

typedef __attribute__((ext_vector_type(8))) short short8;
typedef __attribute__((ext_vector_type(16))) float f32x16;

// frexp-style exponent: for normal m>0, m in [2^(e-1), 2^e); 0/denorm -> -126
__device__ __forceinline__ int fexp_of(float m) {
  return (int)((__float_as_uint(m) >> 23) & 255u) - 126;
}

__device__ __forceinline__ unsigned pk_bf16(float lo, float hi) {
  unsigned r;
  asm("v_cvt_pk_bf16_f32 %0, %1, %2" : "=v"(r) : "v"(lo), "v"(hi));
  return r;
}

// sigma: storage-row permutation so that D-layout rows == next B-frag slots.
__device__ __forceinline__ int SIG(int k) {
  return (k & 3) + 8 * ((k >> 2) & 1) + 4 * ((k >> 3) & 1) + 16 * (k >> 4);
}
// D reg r (0..15) of lane-half h holds true row RHO(r,h)
__device__ __forceinline__ int RHO(int r, int h) {
  return (r & 3) + 8 * (r >> 2) + 4 * h;
}

struct Chain {
  short8 b0, b1;   // current state C in sigma-row-stored bf16 B-frags
  float m[16];     // last D (scaled), f32
  float offs;      // per-column log2 offset (column = lane&31)
};

__device__ __forceinline__ f32x16 mfma2(short8 a0, short8 a1, short8 b0, short8 b1) {
  f32x16 z = {};
  f32x16 d = __builtin_amdgcn_mfma_f32_32x32x16_bf16(a0, b0, z, 0, 0, 0);
  return __builtin_amdgcn_mfma_f32_32x32x16_bf16(a1, b1, d, 0, 0, 0);
}

__device__ __forceinline__ void k1_step(Chain& ch, const float* __restrict__ e,
                                        short8 pa0, short8 pa1, int h, bool rn) {
  const float4* e4 = (const float4*)e;
  float4 e0 = e4[h], e1 = e4[2 + h], e2 = e4[4 + h], e3 = e4[6 + h];
  f32x16 d = mfma2(pa0, pa1, ch.b0, ch.b1);
  ch.m[0] = d[0] * e0.x;  ch.m[1] = d[1] * e0.y;  ch.m[2] = d[2] * e0.z;  ch.m[3] = d[3] * e0.w;
  ch.m[4] = d[4] * e1.x;  ch.m[5] = d[5] * e1.y;  ch.m[6] = d[6] * e1.z;  ch.m[7] = d[7] * e1.w;
  ch.m[8] = d[8] * e2.x;  ch.m[9] = d[9] * e2.y;  ch.m[10] = d[10] * e2.z; ch.m[11] = d[11] * e2.w;
  ch.m[12] = d[12] * e3.x; ch.m[13] = d[13] * e3.y; ch.m[14] = d[14] * e3.z; ch.m[15] = d[15] * e3.w;
  if (rn) {
    float cm = ch.m[0];
#pragma unroll
    for (int i = 1; i < 16; ++i) cm = fmaxf(cm, ch.m[i]);
    cm = fmaxf(cm, __shfl_xor(cm, 32, 64));
    int ex = fexp_of(cm);
    ch.offs += (float)ex;
#pragma unroll
    for (int i = 0; i < 16; ++i) ch.m[i] = ldexpf(ch.m[i], -ex);
  }
  union { unsigned u[4]; short8 s; } B0, B1;
#pragma unroll
  for (int p = 0; p < 4; ++p) {
    B0.u[p] = pk_bf16(ch.m[2 * p], ch.m[2 * p + 1]);
    B1.u[p] = pk_bf16(ch.m[8 + 2 * p], ch.m[8 + 2 * p + 1]);
  }
  ch.b0 = B0.s; ch.b1 = B1.s;
}

__device__ __forceinline__ void init_identity(Chain& ch, int h, int c) {
  union { unsigned u[4]; short8 s; } B0, B1;
#pragma unroll
  for (int p = 0; p < 4; ++p) {
    unsigned lo0 = (SIG(8 * h + 2 * p) == c) ? 0x3F80u : 0u;
    unsigned hi0 = (SIG(8 * h + 2 * p + 1) == c) ? 0x3F80u : 0u;
    B0.u[p] = lo0 | (hi0 << 16);
    unsigned lo1 = (SIG(16 + 8 * h + 2 * p) == c) ? 0x3F80u : 0u;
    unsigned hi1 = (SIG(16 + 8 * h + 2 * p + 1) == c) ? 0x3F80u : 0u;
    B1.u[p] = lo1 | (hi1 << 16);
  }
  ch.b0 = B0.s; ch.b1 = B1.s; ch.offs = 0.f;
#pragma unroll
  for (int i = 0; i < 16; ++i) ch.m[i] = 0.f;
}

// ---------------------------------------------------------------------------
// group_product: G = M_{c0+grp-1} ... M_{c0}, via MFMA, wave-level.
// ---------------------------------------------------------------------------
__device__ __forceinline__ void group_product(
    const float* __restrict__ sm, const float* __restrict__ so,
    int c0, int grp, int h, int c, float m[16], float& offs) {
  const float* m0 = sm + (size_t)c0 * 1024;
#pragma unroll
  for (int r = 0; r < 16; ++r) m[r] = m0[RHO(r, h) * NT + c];
  offs = so[c0 * NT + c];

  for (int gg = 1; gg < grp; ++gg) {
    const float* M = sm + (size_t)(c0 + gg) * 1024;
    const float* O = so + (size_t)(c0 + gg) * NT;
    float af[16];
#pragma unroll
    for (int i = 0; i < 8; ++i) {
      af[i] = M[c * NT + SIG(8 * h + i)];
      af[8 + i] = M[c * NT + SIG(16 + 8 * h + i)];
    }
    float mo = O[c];
    float mm = mo;
#pragma unroll
    for (int dlt = 16; dlt; dlt >>= 1) mm = fmaxf(mm, __shfl_xor(mm, dlt, 64));
    const float4* o4 = (const float4*)O;
    float4 w0 = o4[h], w1 = o4[2 + h], w2 = o4[4 + h], w3 = o4[6 + h];
    float t[16];
    t[0] = m[0] * exp2f(w0.x - mm);  t[1] = m[1] * exp2f(w0.y - mm);
    t[2] = m[2] * exp2f(w0.z - mm);  t[3] = m[3] * exp2f(w0.w - mm);
    t[4] = m[4] * exp2f(w1.x - mm);  t[5] = m[5] * exp2f(w1.y - mm);
    t[6] = m[6] * exp2f(w1.z - mm);  t[7] = m[7] * exp2f(w1.w - mm);
    t[8] = m[8] * exp2f(w2.x - mm);  t[9] = m[9] * exp2f(w2.y - mm);
    t[10] = m[10] * exp2f(w2.z - mm); t[11] = m[11] * exp2f(w2.w - mm);
    t[12] = m[12] * exp2f(w3.x - mm); t[13] = m[13] * exp2f(w3.y - mm);
    t[14] = m[14] * exp2f(w3.z - mm); t[15] = m[15] * exp2f(w3.w - mm);

    union { unsigned u[4]; short8 s; } A0, A1, B0, B1;
#pragma unroll
    for (int p = 0; p < 4; ++p) {
      A0.u[p] = pk_bf16(af[2 * p], af[2 * p + 1]);
      A1.u[p] = pk_bf16(af[8 + 2 * p], af[8 + 2 * p + 1]);
      B0.u[p] = pk_bf16(t[2 * p], t[2 * p + 1]);
      B1.u[p] = pk_bf16(t[8 + 2 * p], t[8 + 2 * p + 1]);
    }
    f32x16 d = mfma2(A0.s, A1.s, B0.s, B1.s);
    float cm = d[0];
#pragma unroll
    for (int i = 1; i < 16; ++i) cm = fmaxf(cm, d[i]);
    cm = fmaxf(cm, __shfl_xor(cm, 32, 64));
    int ex = fexp_of(cm);
#pragma unroll
    for (int i = 0; i < 16; ++i) m[i] = ldexpf(d[i], -ex);
    offs += mm + (float)ex;
  }
}

extern __shared__ float Els[];

// ---------------------------------------------------------------------------
// Fully fused: phase 1 (chunk products) + atomic last-finisher tree combine
// (level1: 16 chunks, level2: 16 groups) + final serial matvec + LSE.
// One wave per block; no spinning; deterministic output.
// ---------------------------------------------------------------------------
__global__ __launch_bounds__(64) void crf_fused(
    const float* __restrict__ feat, const float* __restrict__ trans,
    float* __restrict__ out,
    float* __restrict__ wmat, float* __restrict__ woff,
    float* __restrict__ w2m, float* __restrict__ w2o,
    float* __restrict__ w3m, float* __restrict__ w3o,
    unsigned* __restrict__ ctrs, int lch, int n1, int n2g) {
  const int lane = threadIdx.x;
  const int h = lane >> 5, c = lane & 31;
  const int c0 = blockIdx.x * 2;

  // ---- phase 1: two chunk-matrix chains per wave ----
  {
    const float4* src = (const float4*)(feat + (size_t)c0 * lch * NT);
    float4* dst = (float4*)Els;
    const int n4 = lch * 16;
    for (int k = lane; k < n4; k += 64) {
      float4 v = src[k];
      v.x = exp2f(v.x * L2E); v.y = exp2f(v.y * L2E);
      v.z = exp2f(v.z * L2E); v.w = exp2f(v.w * L2E);
      dst[k] = v;
    }
  }
  short8 pa0, pa1;
  {
    union { unsigned u[4]; short8 s; } A0, A1;
#pragma unroll
    for (int p = 0; p < 4; ++p) {
      float f00 = exp2f(trans[c * NT + SIG(8 * p)] * L2E);       // placeholder, fixed below
      (void)f00;
      break;
    }
    // build properly (loop kept simple & correct):
#pragma unroll
    for (int p = 0; p < 4; ++p) {
      float g00 = exp2f(trans[c * NT + SIG(8 * h + 2 * p)] * L2E);
      float g01 = exp2f(trans[c * NT + SIG(8 * h + 2 * p + 1)] * L2E);
      float g10 = exp2f(trans[c * NT + SIG(16 + 8 * h + 2 * p)] * L2E);
      float g11 = exp2f(trans[c * NT + SIG(16 + 8 * h + 2 * p + 1)] * L2E);
      A0.u[p] = pk_bf16(g00, g01);
      A1.u[p] = pk_bf16(g10, g11);
    }
    pa0 = A0.s; pa1 = A1.s;
  }
  __syncthreads();

  Chain ch0, ch1;
  init_identity(ch0, h, c);
  init_identity(ch1, h, c);
  const float* eb0 = Els;
  const float* eb1 = Els + (size_t)lch * NT;
  for (int s = 0; s < lch; s += 4) {
#pragma unroll
    for (int t = 0; t < 4; ++t) {
      const bool rn = (t == 3);
      k1_step(ch0, eb0 + (s + t) * NT, pa0, pa1, h, rn);
      k1_step(ch1, eb1 + (s + t) * NT, pa0, pa1, h, rn);
    }
  }
  {
    float* wd = wmat + (size_t)c0 * 1024;
#pragma unroll
    for (int r = 0; r < 16; ++r) wd[RHO(r, h) * NT + c] = ch0.m[r];
    if (h == 0) woff[c0 * NT + c] = ch0.offs;
  }
  {
    float* wd = wmat + (size_t)(c0 + 1) * 1024;
#pragma unroll
    for (int r = 0; r < 16; ++r) wd[RHO(r, h) * NT + c] = ch1.m[r];
    if (h == 0) woff[(c0 + 1) * NT + c] = ch1.offs;
  }

  // ---- level 1: last of 8 producer blocks combines 16 chunk matrices ----
  __threadfence();
  const int g = blockIdx.x >> 3;
  int old = 0;
  if (lane == 0) old = (int)atomicAdd(&ctrs[g], 1u);
  old = __shfl(old, 0);
  if (old != 7) return;

  __threadfence();
  float m[16], offs;
  group_product(wmat, woff, g * 16, 16, h, c, m, offs);
  {
    float* wd = w2m + (size_t)g * 1024;
#pragma unroll
    for (int r = 0; r < 16; ++r) wd[RHO(r, h) * NT + c] = m[r];
    if (h == 0) w2o[g * NT + c] = offs;
  }

  // ---- level 2: last of 16 level-1 finishers combines 16 group matrices ----
  __threadfence();
  const int g2 = g >> 4;
  if (lane == 0) old = (int)atomicAdd(&ctrs[n1 + g2], 1u);
  old = __shfl(old, 0);
  if (old != 15) return;

  __threadfence();
  group_product(w2m, w2o, g2 * 16, 16, h, c, m, offs);
  {
    float* wd = w3m + (size_t)g2 * 1024;
#pragma unroll
    for (int r = 0; r < 16; ++r) wd[RHO(r, h) * NT + c] = m[r];
    if (h == 0) w3o[g2 * NT + c] = offs;
  }

  // ---- final: last level-2 finisher applies the n2g matrices serially ----
  __threadfence();
  if (lane == 0) old = (int)atomicAdd(&ctrs[n1 + n2g], 1u);
  old = __shfl(old, 0);
  if (old != n2g - 1) return;

  __threadfence();
  float* uls = Els;  // reuse LDS scratch (single wave)
  float vh = w3m[(size_t)c * NT + START_TAG];  // column START of first group
  float vo = w3o[START_TAG];
  for (int k = 1; k < n2g; ++k) {
    float mo = w3o[k * NT + c];
    float mm = mo;
#pragma unroll
    for (int dlt = 16; dlt; dlt >>= 1) mm = fmaxf(mm, __shfl_xor(mm, dlt, 64));
    if (h == 0) uls[c] = exp2f(mo - mm) * vh;
    asm volatile("s_waitcnt lgkmcnt(0)" ::: "memory");
    float acc = 0.f;
    const float4* Mr = (const float4*)(w3m + (size_t)k * 1024 + c * NT);
    const float4* uu = (const float4*)uls;
#pragma unroll
    for (int p = 0; p < 8; ++p) {
      float4 a = Mr[p]; float4 b = uu[p];
      acc = fmaf(a.x, b.x, fmaf(a.y, b.y, fmaf(a.z, b.z, fmaf(a.w, b.w, acc))));
    }
    float cm = acc;
#pragma unroll
    for (int dlt = 16; dlt; dlt >>= 1) cm = fmaxf(cm, __shfl_xor(cm, dlt, 64));
    int ex = fexp_of(cm);
    vh = ldexpf(acc, -ex);
    vo += mm + (float)ex;
  }
  {
    float ts = trans[STOP_TAG * NT + c] * L2E;
    float tm = ts;
#pragma unroll
    for (int dlt = 16; dlt; dlt >>= 1) tm = fmaxf(tm, __shfl_xor(tm, dlt, 64));
    float term = vh * exp2f(ts - tm);
#pragma unroll
    for (int dlt = 16; dlt; dlt >>= 1) term += __shfl_xor(term, dlt, 64);
    if (lane == 0) out[0] = (vo + tm + log2f(term)) * LN2;
  }
}

extern "C" void kernel_launch(void* const* d_in, const int* in_sizes, int n_in,
                              void* d_out, int out_size, void* d_ws, size_t ws_size,
                              hipStream_t stream) {
  const float* feat = (const float*)d_in[0];
  const float* trans = (const float*)d_in[1];
  float* out = (float*)d_out;

  const int T = in_sizes[0] / NT;  // 65536

  int C = 2048;
  while (C > 256) {
    const int n1t = C / 16, n2t = n1t / 16;
    size_t fl = 256 + (size_t)C * 1056 + (size_t)n1t * 1056 + (size_t)n2t * 1056;
    if (fl * 4 <= ws_size && (T % C) == 0 && ((T / C) % 4) == 0 &&
        n2t >= 1 && (n1t % 16) == 0) break;
    C >>= 1;
  }
  const int lch = T / C;   // 32 for C=2048
  const int n1 = C / 16;   // 128
  const int n2g = n1 / 16; // 8

  unsigned* ctrs = (unsigned*)d_ws;
  float* wmat = (float*)d_ws + 256;  // counters occupy first 1 KB
  float* woff = wmat + (size_t)C * 1024;
  float* w2m  = woff + (size_t)C * 32;
  float* w2o  = w2m + (size_t)n1 * 1024;
  float* w3m  = w2o + (size_t)n1 * 32;
  float* w3o  = w3m + (size_t)n2g * 1024;

  hipMemsetAsync(ctrs, 0, 1024, stream);
  crf_fused<<<C / 2, 64, (size_t)lch * 2 * NT * 4, stream>>>(
      feat, trans, out, wmat, woff, w2m, w2o, w3m, w3o, ctrs, lch, n1, n2g);
}

// Round 4
// 65.130 us; speedup vs baseline: 2.0668x; 2.0668x over previous
//
#include <hip/hip_runtime.h>
#include <hip/hip_bf16.h>

#define NT 32
#define START_TAG 30
#define STOP_TAG 31
#define L2E 1.4426950408889634f
#define LN2 0.6931471805599453f

typedef unsigned short u16;
typedef __attribute__((ext_vector_type(8))) short short8;
typedef __attribute__((ext_vector_type(16))) float f32x16;

// frexp-style exponent: for normal m>0, m in [2^(e-1), 2^e); 0 -> -126
__device__ __forceinline__ int fexp_of(float m) {
  return (int)((__float_as_uint(m) >> 23) & 255u) - 126;
}

__device__ __forceinline__ unsigned pk_bf16(float lo, float hi) {
  unsigned r;
  asm("v_cvt_pk_bf16_f32 %0, %1, %2" : "=v"(r) : "v"(lo), "v"(hi));
  return r;
}

// SIG: swaps bits 2<->3 of a 5-bit index (involution). Chosen so the MFMA
// D-layout rows map 1:1 onto next B-frag slots (verified round 2, absmax 0).
__device__ __forceinline__ int SIG(int k) {
  return (k & 3) + 8 * ((k >> 2) & 1) + 4 * ((k >> 3) & 1) + 16 * (k >> 4);
}
// D reg r (0..15) of lane-half h holds true row RHO(r,h)
__device__ __forceinline__ int RHO(int r, int h) {
  return (r & 3) + 8 * (r >> 2) + 4 * h;
}

__device__ __forceinline__ f32x16 mfma2(short8 a0, short8 a1, short8 b0, short8 b1) {
  f32x16 z = {};
  f32x16 d = __builtin_amdgcn_mfma_f32_32x32x16_bf16(a0, b0, z, 0, 0, 0);
  return __builtin_amdgcn_mfma_f32_32x32x16_bf16(a1, b1, d, 0, 0, 0);
}

// Store m[16] (D-layout, f32) as bf16 matrix in SIG-col-permuted row-major
// layout (A-frag ready), plus per-col f32 offsets (true order) + scalar max.
__device__ __forceinline__ void store_mat(u16* __restrict__ wm, float* __restrict__ wo,
                                          float* __restrict__ wx, const float m[16],
                                          float offs, int h, int c, int lane) {
  __hip_bfloat16* bm = (__hip_bfloat16*)wm;
#pragma unroll
  for (int r = 0; r < 16; ++r)
    bm[RHO(r, h) * NT + SIG(c)] = __float2bfloat16(m[r]);
  if (h == 0) wo[c] = offs;
  float mx = offs;
#pragma unroll
  for (int d = 32; d; d >>= 1) mx = fmaxf(mx, __shfl_xor(mx, d, 64));
  if (lane == 0) wx[0] = mx;
}

struct Chain {
  short8 b0, b1;   // current state C in sigma-row-stored bf16 B-frags
  float m[16];     // last D (scaled), f32
  float offs;      // per-column log2 offset (column = lane&31)
};

__device__ __forceinline__ void k1_step(Chain& ch, const float* __restrict__ e,
                                        short8 pa0, short8 pa1, int h, bool rn) {
  const float4* e4 = (const float4*)e;
  float4 e0 = e4[h], e1 = e4[2 + h], e2 = e4[4 + h], e3 = e4[6 + h];
  f32x16 d = mfma2(pa0, pa1, ch.b0, ch.b1);
  ch.m[0] = d[0] * e0.x;  ch.m[1] = d[1] * e0.y;  ch.m[2] = d[2] * e0.z;  ch.m[3] = d[3] * e0.w;
  ch.m[4] = d[4] * e1.x;  ch.m[5] = d[5] * e1.y;  ch.m[6] = d[6] * e1.z;  ch.m[7] = d[7] * e1.w;
  ch.m[8] = d[8] * e2.x;  ch.m[9] = d[9] * e2.y;  ch.m[10] = d[10] * e2.z; ch.m[11] = d[11] * e2.w;
  ch.m[12] = d[12] * e3.x; ch.m[13] = d[13] * e3.y; ch.m[14] = d[14] * e3.z; ch.m[15] = d[15] * e3.w;
  if (rn) {
    float cm = ch.m[0];
#pragma unroll
    for (int i = 1; i < 16; ++i) cm = fmaxf(cm, ch.m[i]);
    cm = fmaxf(cm, __shfl_xor(cm, 32, 64));
    int ex = fexp_of(cm);
    ch.offs += (float)ex;
#pragma unroll
    for (int i = 0; i < 16; ++i) ch.m[i] = ldexpf(ch.m[i], -ex);
  }
  union { unsigned u[4]; short8 s; } B0, B1;
#pragma unroll
  for (int p = 0; p < 4; ++p) {
    B0.u[p] = pk_bf16(ch.m[2 * p], ch.m[2 * p + 1]);
    B1.u[p] = pk_bf16(ch.m[8 + 2 * p], ch.m[8 + 2 * p + 1]);
  }
  ch.b0 = B0.s; ch.b1 = B1.s;
}

__device__ __forceinline__ void init_identity(Chain& ch, int h, int c) {
  union { unsigned u[4]; short8 s; } B0, B1;
#pragma unroll
  for (int p = 0; p < 4; ++p) {
    unsigned lo0 = (SIG(8 * h + 2 * p) == c) ? 0x3F80u : 0u;
    unsigned hi0 = (SIG(8 * h + 2 * p + 1) == c) ? 0x3F80u : 0u;
    B0.u[p] = lo0 | (hi0 << 16);
    unsigned lo1 = (SIG(16 + 8 * h + 2 * p) == c) ? 0x3F80u : 0u;
    unsigned hi1 = (SIG(16 + 8 * h + 2 * p + 1) == c) ? 0x3F80u : 0u;
    B1.u[p] = lo1 | (hi1 << 16);
  }
  ch.b0 = B0.s; ch.b1 = B1.s; ch.offs = 0.f;
#pragma unroll
  for (int i = 0; i < 16; ++i) ch.m[i] = 0.f;
}

// ---------------------------------------------------------------------------
// K1: 256 threads = 4 waves, each wave runs TWO chunks of LCH steps.
// 8 chunks per block. Short chains + high occupancy hide MFMA latency.
// ---------------------------------------------------------------------------
template <int LCH>
__global__ __launch_bounds__(256) void crf_k1(
    const float* __restrict__ feat, const float* __restrict__ trans,
    u16* __restrict__ wm, float* __restrict__ wo, float* __restrict__ wx) {
  __shared__ __align__(16) float E[8 * LCH * NT];
  const int tid = threadIdx.x, lane = tid & 63, w = tid >> 6;
  const int h = lane >> 5, c = lane & 31;

  // stage E = exp2(feat * log2e) for 8 chunks, coalesced float4
  const float4* src = (const float4*)(feat + (size_t)blockIdx.x * 8 * LCH * NT);
  float4* dst = (float4*)E;
#pragma unroll
  for (int kk = 0; kk < LCH / 4; ++kk) {
    int k = tid + kk * 256;
    float4 v = src[k];
    v.x = exp2f(v.x * L2E); v.y = exp2f(v.y * L2E);
    v.z = exp2f(v.z * L2E); v.w = exp2f(v.w * L2E);
    dst[k] = v;
  }

  // P A-frags, sigma-permuted columns: A0[i] = P[c][SIG(8h+i)], A1: +16
  short8 pa0, pa1;
  {
    union { unsigned u[4]; short8 s; } A0, A1;
#pragma unroll
    for (int p = 0; p < 4; ++p) {
      float g00 = exp2f(trans[c * NT + SIG(8 * h + 2 * p)] * L2E);
      float g01 = exp2f(trans[c * NT + SIG(8 * h + 2 * p + 1)] * L2E);
      float g10 = exp2f(trans[c * NT + SIG(16 + 8 * h + 2 * p)] * L2E);
      float g11 = exp2f(trans[c * NT + SIG(16 + 8 * h + 2 * p + 1)] * L2E);
      A0.u[p] = pk_bf16(g00, g01);
      A1.u[p] = pk_bf16(g10, g11);
    }
    pa0 = A0.s; pa1 = A1.s;
  }
  __syncthreads();

  Chain ch0, ch1;
  init_identity(ch0, h, c);
  init_identity(ch1, h, c);
  const float* eb0 = E + (size_t)(2 * w) * LCH * NT;
  const float* eb1 = E + (size_t)(2 * w + 1) * LCH * NT;
#pragma unroll
  for (int s = 0; s < LCH; s += 4) {
#pragma unroll
    for (int t = 0; t < 4; ++t) {
      const bool rn = (t == 3);
      k1_step(ch0, eb0 + (s + t) * NT, pa0, pa1, h, rn);
      k1_step(ch1, eb1 + (s + t) * NT, pa0, pa1, h, rn);
    }
  }

  const int c0 = blockIdx.x * 8 + 2 * w;
  store_mat(wm + (size_t)c0 * 1024, wo + (size_t)c0 * NT, wx + c0,
            ch0.m, ch0.offs, h, c, lane);
  store_mat(wm + (size_t)(c0 + 1) * 1024, wo + (size_t)(c0 + 1) * NT, wx + c0 + 1,
            ch1.m, ch1.offs, h, c, lane);
}

// ---------------------------------------------------------------------------
// gprod: m = M_{c0+grp-1} ... M_{c0} from identity, via MFMA.
// A-side loads are two aligned dwordx4 (stored layout is A-frag ready);
// offset scaling uses producer-stored scalar max (no shuffle in the loop).
// ---------------------------------------------------------------------------
__device__ __forceinline__ void gprod(
    const u16* __restrict__ sm, const float* __restrict__ so,
    const float* __restrict__ sx, int c0, int grp, int h, int c,
    float m[16], float& offs) {
#pragma unroll
  for (int r = 0; r < 16; ++r) m[r] = (RHO(r, h) == c) ? 1.f : 0.f;
  offs = 0.f;

#pragma unroll 4
  for (int gg = 0; gg < grp; ++gg) {
    const u16* rowp = sm + (size_t)(c0 + gg) * 1024 + c * NT;
    short8 a0 = *(const short8*)(rowp + 8 * h);
    short8 a1 = *(const short8*)(rowp + 16 + 8 * h);
    const float* O = so + (size_t)(c0 + gg) * NT;
    const float mmax = sx[c0 + gg];
    const float4* o4 = (const float4*)O;
    float4 w0 = o4[h], w1 = o4[2 + h], w2 = o4[4 + h], w3 = o4[6 + h];
    float t[16];
    t[0]  = ldexpf(m[0],  (int)(w0.x - mmax)); t[1]  = ldexpf(m[1],  (int)(w0.y - mmax));
    t[2]  = ldexpf(m[2],  (int)(w0.z - mmax)); t[3]  = ldexpf(m[3],  (int)(w0.w - mmax));
    t[4]  = ldexpf(m[4],  (int)(w1.x - mmax)); t[5]  = ldexpf(m[5],  (int)(w1.y - mmax));
    t[6]  = ldexpf(m[6],  (int)(w1.z - mmax)); t[7]  = ldexpf(m[7],  (int)(w1.w - mmax));
    t[8]  = ldexpf(m[8],  (int)(w2.x - mmax)); t[9]  = ldexpf(m[9],  (int)(w2.y - mmax));
    t[10] = ldexpf(m[10], (int)(w2.z - mmax)); t[11] = ldexpf(m[11], (int)(w2.w - mmax));
    t[12] = ldexpf(m[12], (int)(w3.x - mmax)); t[13] = ldexpf(m[13], (int)(w3.y - mmax));
    t[14] = ldexpf(m[14], (int)(w3.z - mmax)); t[15] = ldexpf(m[15], (int)(w3.w - mmax));

    union { unsigned u[4]; short8 s; } B0, B1;
#pragma unroll
    for (int p = 0; p < 4; ++p) {
      B0.u[p] = pk_bf16(t[2 * p], t[2 * p + 1]);
      B1.u[p] = pk_bf16(t[8 + 2 * p], t[8 + 2 * p + 1]);
    }
    f32x16 d = mfma2(a0, a1, B0.s, B1.s);
    float cm = d[0];
#pragma unroll
    for (int i = 1; i < 16; ++i) cm = fmaxf(cm, d[i]);
    cm = fmaxf(cm, __shfl_xor(cm, 32, 64));
    int ex = fexp_of(cm);
#pragma unroll
    for (int i = 0; i < 16; ++i) m[i] = ldexpf(d[i], -ex);
    offs += mmax + (float)ex;
  }
}

__global__ __launch_bounds__(64) void crf_kc(
    const u16* __restrict__ sm, const float* __restrict__ so,
    const float* __restrict__ sx, u16* __restrict__ dm,
    float* __restrict__ dof, float* __restrict__ dx, int grp) {
  const int lane = threadIdx.x;
  const int h = lane >> 5, c = lane & 31;
  const int g = blockIdx.x;
  float m[16], offs;
  gprod(sm, so, sx, g * grp, grp, h, c, m, offs);
  store_mat(dm + (size_t)g * 1024, dof + (size_t)g * NT, dx + g, m, offs, h, c, lane);
}

// Final: product of the last `grp` matrices, then terminal LSE on column START.
__global__ __launch_bounds__(64) void crf_k3(
    const u16* __restrict__ sm, const float* __restrict__ so,
    const float* __restrict__ sx, const float* __restrict__ trans,
    float* __restrict__ out, int grp) {
  const int lane = threadIdx.x;
  const int h = lane >> 5, c = lane & 31;
  float m[16], offs;
  gprod(sm, so, sx, 0, grp, h, c, m, offs);

  float ts[16];
  float tm = -1e30f;
#pragma unroll
  for (int r = 0; r < 16; ++r) {
    ts[r] = trans[STOP_TAG * NT + RHO(r, h)] * L2E;
    tm = fmaxf(tm, ts[r]);
  }
  tm = fmaxf(tm, __shfl_xor(tm, 32, 64));
  float s = 0.f;
#pragma unroll
  for (int r = 0; r < 16; ++r) s += m[r] * exp2f(ts[r] - tm);
  s += __shfl_xor(s, 32, 64);
  if (lane == START_TAG) out[0] = (offs + tm + log2f(s)) * LN2;
}

extern "C" void kernel_launch(void* const* d_in, const int* in_sizes, int n_in,
                              void* d_out, int out_size, void* d_ws, size_t ws_size,
                              hipStream_t stream) {
  const float* feat = (const float*)d_in[0];
  const float* trans = (const float*)d_in[1];
  float* out = (float*)d_out;

  const int T = in_sizes[0] / NT;  // 65536

  int C = 8192;
  for (;;) {
    const size_t n1t = (size_t)C / 32;
    const size_t need = (size_t)C * 2048 + (size_t)C * 128 + (size_t)C * 4 +
                        n1t * 2048 + n1t * 128 + n1t * 4 +
                        8 * 2048 + 8 * 128 + 8 * 4 + 4096;
    if (C <= 2048) break;
    if (need <= ws_size && (T % C) == 0 && ((T / C) % 4) == 0 && (C % 256) == 0)
      break;
    C >>= 1;
  }
  const int lch = T / C;      // 8 / 16 / 32
  const int n1 = C / 32;      // 256 / 128 / 64
  const int grp2 = n1 / 8;    // 32 / 16 / 8

  char* p = (char*)d_ws;
  u16* wm = (u16*)p;    p += (size_t)C * 2048;
  float* wo = (float*)p; p += (size_t)C * 128;
  float* wx = (float*)p; p += (size_t)C * 4;
  u16* l1m = (u16*)p;   p += (size_t)n1 * 2048;
  float* l1o = (float*)p; p += (size_t)n1 * 128;
  float* l1x = (float*)p; p += (size_t)n1 * 4;
  u16* l2m = (u16*)p;   p += 8 * 2048;
  float* l2o = (float*)p; p += 8 * 128;
  float* l2x = (float*)p;

  if (lch == 8)
    crf_k1<8><<<C / 8, 256, 0, stream>>>(feat, trans, wm, wo, wx);
  else if (lch == 16)
    crf_k1<16><<<C / 8, 256, 0, stream>>>(feat, trans, wm, wo, wx);
  else
    crf_k1<32><<<C / 8, 256, 0, stream>>>(feat, trans, wm, wo, wx);

  crf_kc<<<n1, 64, 0, stream>>>(wm, wo, wx, l1m, l1o, l1x, 32);
  crf_kc<<<8, 64, 0, stream>>>(l1m, l1o, l1x, l2m, l2o, l2x, grp2);
  crf_k3<<<1, 64, 0, stream>>>(l2m, l2o, l2x, trans, out, 8);
}

// Round 6
// 42.540 us; speedup vs baseline: 3.1644x; 1.5311x over previous
//
#include <hip/hip_runtime.h>
#include <hip/hip_bf16.h>

#define NT 32
#define START_TAG 30
#define STOP_TAG 31
#define L2E 1.4426950408889634f
#define LN2 0.6931471805599453f
#define FW 8   // finisher waves

typedef unsigned short u16;
typedef __attribute__((ext_vector_type(8))) short short8;
typedef __attribute__((ext_vector_type(16))) float f32x16;

// frexp-style exponent: for normal m>0, m in [2^(e-1), 2^e); 0 -> -126
__device__ __forceinline__ int fexp_of(float m) {
  return (int)((__float_as_uint(m) >> 23) & 255u) - 126;
}

__device__ __forceinline__ unsigned pk_bf16(float lo, float hi) {
  unsigned r;
  asm("v_cvt_pk_bf16_f32 %0, %1, %2" : "=v"(r) : "v"(lo), "v"(hi));
  return r;
}

// SIG: swaps bits 2<->3 of a 5-bit index (involution). Chosen so the MFMA
// D-layout rows map 1:1 onto next B-frag slots (verified rounds 2-4, absmax 0).
__device__ __forceinline__ int SIG(int k) {
  return (k & 3) + 8 * ((k >> 2) & 1) + 4 * ((k >> 3) & 1) + 16 * (k >> 4);
}
// D reg r (0..15) of lane-half h holds true row RHO(r,h)
__device__ __forceinline__ int RHO(int r, int h) {
  return (r & 3) + 8 * (r >> 2) + 4 * h;
}

__device__ __forceinline__ f32x16 mfma2(short8 a0, short8 a1, short8 b0, short8 b1) {
  f32x16 z = {};
  f32x16 d = __builtin_amdgcn_mfma_f32_32x32x16_bf16(a0, b0, z, 0, 0, 0);
  return __builtin_amdgcn_mfma_f32_32x32x16_bf16(a1, b1, d, 0, 0, 0);
}

// Store m[16] (D-layout, f32) as bf16 matrix in SIG-col-permuted row-major
// layout (A-frag ready), plus per-col f32 offsets (true order) + scalar max.
__device__ __forceinline__ void store_mat(u16* __restrict__ wm, float* __restrict__ wo,
                                          float* __restrict__ wx, const float m[16],
                                          float offs, int h, int c, int lane) {
  __hip_bfloat16* bm = (__hip_bfloat16*)wm;
#pragma unroll
  for (int r = 0; r < 16; ++r)
    bm[RHO(r, h) * NT + SIG(c)] = __float2bfloat16(m[r]);
  if (h == 0) wo[c] = offs;
  float mx = offs;
#pragma unroll
  for (int d = 32; d; d >>= 1) mx = fmaxf(mx, __shfl_xor(mx, d, 64));
  if (lane == 0) wx[0] = mx;
}

struct Chain {
  short8 b0, b1;   // current state C in sigma-row-stored bf16 B-frags
  float m[16];     // last D (scaled), f32
  float offs;      // per-column log2 offset (column = lane&31)
};

__device__ __forceinline__ void k1_step(Chain& ch, const float* __restrict__ e,
                                        short8 pa0, short8 pa1, int h, bool rn) {
  const float4* e4 = (const float4*)e;
  float4 e0 = e4[h], e1 = e4[2 + h], e2 = e4[4 + h], e3 = e4[6 + h];
  f32x16 d = mfma2(pa0, pa1, ch.b0, ch.b1);
  ch.m[0] = d[0] * e0.x;  ch.m[1] = d[1] * e0.y;  ch.m[2] = d[2] * e0.z;  ch.m[3] = d[3] * e0.w;
  ch.m[4] = d[4] * e1.x;  ch.m[5] = d[5] * e1.y;  ch.m[6] = d[6] * e1.z;  ch.m[7] = d[7] * e1.w;
  ch.m[8] = d[8] * e2.x;  ch.m[9] = d[9] * e2.y;  ch.m[10] = d[10] * e2.z; ch.m[11] = d[11] * e2.w;
  ch.m[12] = d[12] * e3.x; ch.m[13] = d[13] * e3.y; ch.m[14] = d[14] * e3.z; ch.m[15] = d[15] * e3.w;
  if (rn) {
    float cm = ch.m[0];
#pragma unroll
    for (int i = 1; i < 16; ++i) cm = fmaxf(cm, ch.m[i]);
    cm = fmaxf(cm, __shfl_xor(cm, 32, 64));
    int ex = fexp_of(cm);
    ch.offs += (float)ex;
#pragma unroll
    for (int i = 0; i < 16; ++i) ch.m[i] = ldexpf(ch.m[i], -ex);
  }
  union { unsigned u[4]; short8 s; } B0, B1;
#pragma unroll
  for (int p = 0; p < 4; ++p) {
    B0.u[p] = pk_bf16(ch.m[2 * p], ch.m[2 * p + 1]);
    B1.u[p] = pk_bf16(ch.m[8 + 2 * p], ch.m[8 + 2 * p + 1]);
  }
  ch.b0 = B0.s; ch.b1 = B1.s;
}

__device__ __forceinline__ void init_identity(Chain& ch, int h, int c) {
  union { unsigned u[4]; short8 s; } B0, B1;
#pragma unroll
  for (int p = 0; p < 4; ++p) {
    unsigned lo0 = (SIG(8 * h + 2 * p) == c) ? 0x3F80u : 0u;
    unsigned hi0 = (SIG(8 * h + 2 * p + 1) == c) ? 0x3F80u : 0u;
    B0.u[p] = lo0 | (hi0 << 16);
    unsigned lo1 = (SIG(16 + 8 * h + 2 * p) == c) ? 0x3F80u : 0u;
    unsigned hi1 = (SIG(16 + 8 * h + 2 * p + 1) == c) ? 0x3F80u : 0u;
    B1.u[p] = lo1 | (hi1 << 16);
  }
  ch.b0 = B0.s; ch.b1 = B1.s; ch.offs = 0.f;
#pragma unroll
  for (int i = 0; i < 16; ++i) ch.m[i] = 0.f;
}

// ---------------------------------------------------------------------------
// K1: 256 threads = 4 waves, each wave runs TWO chunks of LCH steps.
// 8 chunks per block. (Structure identical to rounds 4 passing run.)
// ---------------------------------------------------------------------------
template <int LCH>
__global__ __launch_bounds__(256) void crf_k1(
    const float* __restrict__ feat, const float* __restrict__ trans,
    u16* __restrict__ wm, float* __restrict__ wo, float* __restrict__ wx) {
  __shared__ __align__(16) float E[8 * LCH * NT];
  const int tid = threadIdx.x, lane = tid & 63, w = tid >> 6;
  const int h = lane >> 5, c = lane & 31;

  // stage E = exp2(feat * log2e) for 8 chunks, coalesced float4
  const float4* src = (const float4*)(feat + (size_t)blockIdx.x * 8 * LCH * NT);
  float4* dst = (float4*)E;
#pragma unroll
  for (int kk = 0; kk < LCH / 4; ++kk) {
    int k = tid + kk * 256;
    float4 v = src[k];
    v.x = exp2f(v.x * L2E); v.y = exp2f(v.y * L2E);
    v.z = exp2f(v.z * L2E); v.w = exp2f(v.w * L2E);
    dst[k] = v;
  }

  // P A-frags, sigma-permuted columns: A0[i] = P[c][SIG(8h+i)], A1: +16
  short8 pa0, pa1;
  {
    union { unsigned u[4]; short8 s; } A0, A1;
#pragma unroll
    for (int p = 0; p < 4; ++p) {
      float g00 = exp2f(trans[c * NT + SIG(8 * h + 2 * p)] * L2E);
      float g01 = exp2f(trans[c * NT + SIG(8 * h + 2 * p + 1)] * L2E);
      float g10 = exp2f(trans[c * NT + SIG(16 + 8 * h + 2 * p)] * L2E);
      float g11 = exp2f(trans[c * NT + SIG(16 + 8 * h + 2 * p + 1)] * L2E);
      A0.u[p] = pk_bf16(g00, g01);
      A1.u[p] = pk_bf16(g10, g11);
    }
    pa0 = A0.s; pa1 = A1.s;
  }
  __syncthreads();

  Chain ch0, ch1;
  init_identity(ch0, h, c);
  init_identity(ch1, h, c);
  const float* eb0 = E + (size_t)(2 * w) * LCH * NT;
  const float* eb1 = E + (size_t)(2 * w + 1) * LCH * NT;
#pragma unroll
  for (int s = 0; s < LCH; s += 4) {
#pragma unroll
    for (int t = 0; t < 4; ++t) {
      const bool rn = (t == 3);
      k1_step(ch0, eb0 + (s + t) * NT, pa0, pa1, h, rn);
      k1_step(ch1, eb1 + (s + t) * NT, pa0, pa1, h, rn);
    }
  }

  const int c0 = blockIdx.x * 8 + 2 * w;
  store_mat(wm + (size_t)c0 * 1024, wo + (size_t)c0 * NT, wx + c0,
            ch0.m, ch0.offs, h, c, lane);
  store_mat(wm + (size_t)(c0 + 1) * 1024, wo + (size_t)(c0 + 1) * NT, wx + c0 + 1,
            ch1.m, ch1.offs, h, c, lane);
}

// ---------------------------------------------------------------------------
// gprod (GLOBAL sources only — as proven in round 4): serial left-multiply
// chain m = M_{c0+grp-1} ... M_{c0}.
// ---------------------------------------------------------------------------
__device__ __forceinline__ void gprod(
    const u16* __restrict__ sm, const float* __restrict__ so,
    const float* __restrict__ sx, int c0, int grp, int h, int c,
    float m[16], float& offs) {
#pragma unroll
  for (int r = 0; r < 16; ++r) m[r] = (RHO(r, h) == c) ? 1.f : 0.f;
  offs = 0.f;

#pragma unroll 4
  for (int gg = 0; gg < grp; ++gg) {
    const u16* rowp = sm + (size_t)(c0 + gg) * 1024 + c * NT;
    short8 a0 = *(const short8*)(rowp + 8 * h);
    short8 a1 = *(const short8*)(rowp + 16 + 8 * h);
    const float* O = so + (size_t)(c0 + gg) * NT;
    const float mmax = sx[c0 + gg];
    const float4* o4 = (const float4*)O;
    float4 w0 = o4[h], w1 = o4[2 + h], w2 = o4[4 + h], w3 = o4[6 + h];
    float t[16];
    t[0]  = ldexpf(m[0],  (int)(w0.x - mmax)); t[1]  = ldexpf(m[1],  (int)(w0.y - mmax));
    t[2]  = ldexpf(m[2],  (int)(w0.z - mmax)); t[3]  = ldexpf(m[3],  (int)(w0.w - mmax));
    t[4]  = ldexpf(m[4],  (int)(w1.x - mmax)); t[5]  = ldexpf(m[5],  (int)(w1.y - mmax));
    t[6]  = ldexpf(m[6],  (int)(w1.z - mmax)); t[7]  = ldexpf(m[7],  (int)(w1.w - mmax));
    t[8]  = ldexpf(m[8],  (int)(w2.x - mmax)); t[9]  = ldexpf(m[9],  (int)(w2.y - mmax));
    t[10] = ldexpf(m[10], (int)(w2.z - mmax)); t[11] = ldexpf(m[11], (int)(w2.w - mmax));
    t[12] = ldexpf(m[12], (int)(w3.x - mmax)); t[13] = ldexpf(m[13], (int)(w3.y - mmax));
    t[14] = ldexpf(m[14], (int)(w3.z - mmax)); t[15] = ldexpf(m[15], (int)(w3.w - mmax));

    union { unsigned u[4]; short8 s; } B0, B1;
#pragma unroll
    for (int p = 0; p < 4; ++p) {
      B0.u[p] = pk_bf16(t[2 * p], t[2 * p + 1]);
      B1.u[p] = pk_bf16(t[8 + 2 * p], t[8 + 2 * p + 1]);
    }
    f32x16 d = mfma2(a0, a1, B0.s, B1.s);
    float cm = d[0];
#pragma unroll
    for (int i = 1; i < 16; ++i) cm = fmaxf(cm, d[i]);
    cm = fmaxf(cm, __shfl_xor(cm, 32, 64));
    int ex = fexp_of(cm);
#pragma unroll
    for (int i = 0; i < 16; ++i) m[i] = ldexpf(d[i], -ex);
    offs += mmax + (float)ex;
  }
}

__global__ __launch_bounds__(64) void crf_kc(
    const u16* __restrict__ sm, const float* __restrict__ so,
    const float* __restrict__ sx, u16* __restrict__ dm,
    float* __restrict__ dof, float* __restrict__ dx, int grp) {
  const int lane = threadIdx.x;
  const int h = lane >> 5, c = lane & 31;
  const int g = blockIdx.x;
  float m[16], offs;
  gprod(sm, so, sx, g * grp, grp, h, c, m, offs);
  store_mat(dm + (size_t)g * 1024, dof + (size_t)g * NT, dx + g, m, offs, h, c, lane);
}

// ---------------------------------------------------------------------------
// K3g finisher: 8 waves (512 thr) each gprod 1/8 of the l1 matrices from
// GLOBAL (proven path), stage partials to LDS as plain f32 row-major.
// Wave 0 then folds the 8 partials serially (round-2-style f32 A-gather,
// scalar LDS indexing) and does the terminal LSE.
// ---------------------------------------------------------------------------
__global__ __launch_bounds__(512) void crf_k3g(
    const u16* __restrict__ sm, const float* __restrict__ so,
    const float* __restrict__ sx, const float* __restrict__ trans,
    float* __restrict__ out, int n1) {
  const int tid = threadIdx.x, w = tid >> 6, lane = tid & 63;
  const int h = lane >> 5, c = lane & 31;
  __shared__ __align__(16) float Gls[FW][NT * NT];
  __shared__ __align__(16) float Ools[FW][NT];
  __shared__ float Xls[FW];

  {
    const int per = n1 / FW;
    float m[16], offs;
    gprod(sm, so, sx, w * per, per, h, c, m, offs);
#pragma unroll
    for (int r = 0; r < 16; ++r) Gls[w][RHO(r, h) * NT + c] = m[r];
    if (h == 0) Ools[w][c] = offs;
    float mx = offs;
#pragma unroll
    for (int d = 32; d; d >>= 1) mx = fmaxf(mx, __shfl_xor(mx, d, 64));
    if (lane == 0) Xls[w] = mx;
  }
  __syncthreads();

  if (w == 0) {
    float g[16], go;
#pragma unroll
    for (int r = 0; r < 16; ++r) g[r] = Gls[0][RHO(r, h) * NT + c];
    go = Ools[0][c];

    for (int gg = 1; gg < FW; ++gg) {
      float af[16];
#pragma unroll
      for (int i = 0; i < 8; ++i) {
        af[i]     = Gls[gg][c * NT + SIG(8 * h + i)];
        af[8 + i] = Gls[gg][c * NT + SIG(16 + 8 * h + i)];
      }
      const float mmax = Xls[gg];
      float t[16];
#pragma unroll
      for (int r = 0; r < 16; ++r)
        t[r] = ldexpf(g[r], (int)(Ools[gg][RHO(r, h)] - mmax));

      union { unsigned u[4]; short8 s; } A0, A1, B0, B1;
#pragma unroll
      for (int p = 0; p < 4; ++p) {
        A0.u[p] = pk_bf16(af[2 * p], af[2 * p + 1]);
        A1.u[p] = pk_bf16(af[8 + 2 * p], af[8 + 2 * p + 1]);
        B0.u[p] = pk_bf16(t[2 * p], t[2 * p + 1]);
        B1.u[p] = pk_bf16(t[8 + 2 * p], t[8 + 2 * p + 1]);
      }
      f32x16 d = mfma2(A0.s, A1.s, B0.s, B1.s);
      float cm = d[0];
#pragma unroll
      for (int i = 1; i < 16; ++i) cm = fmaxf(cm, d[i]);
      cm = fmaxf(cm, __shfl_xor(cm, 32, 64));
      int ex = fexp_of(cm);
#pragma unroll
      for (int i = 0; i < 16; ++i) g[i] = ldexpf(d[i], -ex);
      go += mmax + (float)ex;
    }

    // terminal LSE: out = ln( sum_j 2^{ts_j} * G[j][START] * 2^{go_START} )
    float ts[16];
    float tm = -1e30f;
#pragma unroll
    for (int r = 0; r < 16; ++r) {
      ts[r] = trans[STOP_TAG * NT + RHO(r, h)] * L2E;
      tm = fmaxf(tm, ts[r]);
    }
    tm = fmaxf(tm, __shfl_xor(tm, 32, 64));
    float s = 0.f;
#pragma unroll
    for (int r = 0; r < 16; ++r) s += g[r] * exp2f(ts[r] - tm);
    s += __shfl_xor(s, 32, 64);
    if (lane == START_TAG) out[0] = (go + tm + log2f(s)) * LN2;
  }
}

extern "C" void kernel_launch(void* const* d_in, const int* in_sizes, int n_in,
                              void* d_out, int out_size, void* d_ws, size_t ws_size,
                              hipStream_t stream) {
  const float* feat = (const float*)d_in[0];
  const float* trans = (const float*)d_in[1];
  float* out = (float*)d_out;

  const int T = in_sizes[0] / NT;  // 65536

  int C = 2048;
  for (;;) {
    const size_t n1t = (size_t)C / 16;
    const size_t need = (size_t)C * 2048 + (size_t)C * 128 + (size_t)C * 4 +
                        n1t * 2048 + n1t * 128 + n1t * 4 + 4096;
    if (C <= 512) break;
    if (need <= ws_size && (T % C) == 0 && ((T / C) % 4) == 0 &&
        (C % 256) == 0 && (n1t % FW) == 0 && (T / C) <= 64)
      break;
    C >>= 1;
  }
  const int lch = T / C;   // 32 for T=65536
  const int n1 = C / 16;   // 128

  char* p = (char*)d_ws;
  u16* wm = (u16*)p;     p += (size_t)C * 2048;
  float* wo = (float*)p; p += (size_t)C * 128;
  float* wx = (float*)p; p += (size_t)C * 4;
  u16* l1m = (u16*)p;    p += (size_t)n1 * 2048;
  float* l1o = (float*)p; p += (size_t)n1 * 128;
  float* l1x = (float*)p;

  if (lch == 16)
    crf_k1<16><<<C / 8, 256, 0, stream>>>(feat, trans, wm, wo, wx);
  else if (lch == 32)
    crf_k1<32><<<C / 8, 256, 0, stream>>>(feat, trans, wm, wo, wx);
  else
    crf_k1<64><<<C / 8, 256, 0, stream>>>(feat, trans, wm, wo, wx);

  crf_kc<<<n1, 64, 0, stream>>>(wm, wo, wx, l1m, l1o, l1x, 16);
  crf_k3g<<<1, 512, 0, stream>>>(l1m, l1o, l1x, trans, out, n1);
}